// Round 1
// baseline (395.414 us; speedup 1.0000x reference)
//
#include <hip/hip_runtime.h>
#include <cstdint>

#define B_ 2
#define S_ 2048
#define D_ 1024
#define H_ 16
#define DH_ 64

typedef short bf16x8 __attribute__((ext_vector_type(8)));
typedef float f32x4 __attribute__((ext_vector_type(4)));

__device__ inline unsigned short f2bf(float f) {
  unsigned int u = __float_as_uint(f);
  u += 0x7fffu + ((u >> 16) & 1u);
  return (unsigned short)(u >> 16);
}

// ---------- cast fp32 -> bf16, vectorized x4 ----------
__global__ __launch_bounds__(256) void k_cast(const float* __restrict__ in,
                                              unsigned short* __restrict__ out, int n4) {
  int i = blockIdx.x * 256 + threadIdx.x;
  if (i >= n4) return;
  float4 v = reinterpret_cast<const float4*>(in)[i];
  ushort4 o;
  o.x = f2bf(v.x); o.y = f2bf(v.y); o.z = f2bf(v.z); o.w = f2bf(v.w);
  reinterpret_cast<ushort4*>(out)[i] = o;
}

// ---------- transpose + cast fp32 [R][C] -> bf16 [C][R] ----------
__global__ __launch_bounds__(256) void k_trcast(const float* __restrict__ in,
                                                unsigned short* __restrict__ out,
                                                int R, int C) {
  __shared__ float tile[32][33];
  int ct = blockIdx.x * 32, rt = blockIdx.y * 32;
  int tx = threadIdx.x, ty = threadIdx.y;
#pragma unroll
  for (int i = 0; i < 32; i += 8)
    tile[ty + i][tx] = in[(size_t)(rt + ty + i) * C + ct + tx];
  __syncthreads();
#pragma unroll
  for (int i = 0; i < 32; i += 8)
    out[(size_t)(ct + ty + i) * R + rt + tx] = f2bf(tile[tx][ty + i]);
}

// ---------- batched transpose of V slice of qkv -> VT[b,h,dh,s] (bf16) ----------
__global__ __launch_bounds__(256) void k_vt(const unsigned short* __restrict__ qkv,
                                            unsigned short* __restrict__ VT) {
  __shared__ unsigned short tile[32][33];
  int bh = blockIdx.z;
  int b = bh >> 4, h = bh & 15;
  const unsigned short* in = qkv + (size_t)b * S_ * 3072 + 2048 + h * 64;
  unsigned short* out = VT + (size_t)bh * DH_ * S_;
  int st0 = blockIdx.x * 32, dt0 = blockIdx.y * 32;
  int tx = threadIdx.x, ty = threadIdx.y;
#pragma unroll
  for (int i = 0; i < 32; i += 8)
    tile[ty + i][tx] = in[(size_t)(st0 + ty + i) * 3072 + dt0 + tx];
  __syncthreads();
#pragma unroll
  for (int i = 0; i < 32; i += 8)
    out[(size_t)(dt0 + ty + i) * S_ + st0 + tx] = tile[tx][ty + i];
}

// ---------- bf16 GEMM: C[M][N] = A[M][K] * BT[N][K]^T + bias ----------
// 128x128 tile, BK=64, 4 waves (2x2), each wave 64x64 via 16x16x32 MFMA.
template <typename OutT>
__global__ __launch_bounds__(256) void k_gemm(const unsigned short* __restrict__ A,
                                              const unsigned short* __restrict__ BT,
                                              const float* __restrict__ bias,
                                              OutT* __restrict__ C,
                                              int M, int N, int K) {
  __shared__ unsigned short As[128 * 64];
  __shared__ unsigned short Bs[128 * 64];
  const int t = threadIdx.x;
  const int lane = t & 63;
  const int wave = t >> 6;
  const int wm = wave >> 1, wn = wave & 1;
  const int ln15 = lane & 15, lg = lane >> 4;
  const int row0 = blockIdx.x * 128, col0 = blockIdx.y * 128;
  f32x4 acc[4][4];
#pragma unroll
  for (int i = 0; i < 4; ++i)
#pragma unroll
    for (int j = 0; j < 4; ++j)
      acc[i][j] = (f32x4){0.f, 0.f, 0.f, 0.f};

  for (int k0 = 0; k0 < K; k0 += 64) {
    __syncthreads();
#pragma unroll
    for (int i = 0; i < 4; ++i) {
      int chunk = i * 256 + t;          // 16-byte chunks; 8 chunks per 64-col row
      int r = chunk >> 3;
      int cb = (chunk & 7) * 16;
      const char* ga = (const char*)(A + (size_t)(row0 + r) * K + k0) + cb;
      const char* gb = (const char*)(BT + (size_t)(col0 + r) * K + k0) + cb;
      __builtin_amdgcn_global_load_lds(
          (const __attribute__((address_space(1))) unsigned int*)ga,
          (__attribute__((address_space(3))) unsigned int*)((char*)As + chunk * 16), 16, 0, 0);
      __builtin_amdgcn_global_load_lds(
          (const __attribute__((address_space(1))) unsigned int*)gb,
          (__attribute__((address_space(3))) unsigned int*)((char*)Bs + chunk * 16), 16, 0, 0);
    }
    __syncthreads();
#pragma unroll
    for (int ks = 0; ks < 2; ++ks) {
      bf16x8 af[4], bf[4];
#pragma unroll
      for (int mt = 0; mt < 4; ++mt)
        af[mt] = *(const bf16x8*)&As[(wm * 64 + mt * 16 + ln15) * 64 + ks * 32 + lg * 8];
#pragma unroll
      for (int nt = 0; nt < 4; ++nt)
        bf[nt] = *(const bf16x8*)&Bs[(wn * 64 + nt * 16 + ln15) * 64 + ks * 32 + lg * 8];
#pragma unroll
      for (int mt = 0; mt < 4; ++mt)
#pragma unroll
        for (int nt = 0; nt < 4; ++nt)
          acc[mt][nt] = __builtin_amdgcn_mfma_f32_16x16x32_bf16(af[mt], bf[nt], acc[mt][nt], 0, 0, 0);
    }
  }
  // epilogue: C/D layout col=lane&15, row=(lane>>4)*4+reg  [measured m89]
#pragma unroll
  for (int mt = 0; mt < 4; ++mt) {
#pragma unroll
    for (int nt = 0; nt < 4; ++nt) {
      int col = col0 + wn * 64 + nt * 16 + ln15;
      float bv = bias[col];
#pragma unroll
      for (int r = 0; r < 4; ++r) {
        int row = row0 + wm * 64 + mt * 16 + lg * 4 + r;
        float v = acc[mt][nt][r] + bv;
        if constexpr (sizeof(OutT) == 2)
          C[(size_t)row * N + col] = f2bf(v);
        else
          C[(size_t)row * N + col] = v;
      }
    }
  }
}

// ---------- flash attention ----------
// grid: (S/64, B*H); 4 waves, each wave owns 16 q-rows.
// Swapped QK^T: st = mfma(K_frag, Q_frag) so a q-row's scores live in a
// 16-lane column group -> row reduce = 2x shfl_xor.
__global__ __launch_bounds__(256) void k_attn(const unsigned short* __restrict__ qkv,
                                              const unsigned short* __restrict__ VT,
                                              unsigned short* __restrict__ O) {
  __shared__ unsigned short Plds[4][16 * 32];
  const int bh = blockIdx.y;
  const int b = bh >> 4, h = bh & 15;
  const int t = threadIdx.x, wave = t >> 6, lane = t & 63;
  const int ln15 = lane & 15, lg = lane >> 4;
  const int qrow = blockIdx.x * 64 + wave * 16 + ln15;  // q index within (b,h)
  const unsigned short* Qb = qkv + (size_t)b * S_ * 3072 + h * 64;          // row stride 3072
  const unsigned short* Kb = Qb + 1024;
  const unsigned short* Vb = VT + (size_t)bh * DH_ * S_;                    // [64][2048]
  const float sc = 0.125f;  // 1/sqrt(64)

  bf16x8 qf[2];
#pragma unroll
  for (int ks = 0; ks < 2; ++ks)
    qf[ks] = *(const bf16x8*)&Qb[(size_t)qrow * 3072 + ks * 32 + lg * 8];

  f32x4 acc[4];
#pragma unroll
  for (int i = 0; i < 4; ++i) acc[i] = (f32x4){0.f, 0.f, 0.f, 0.f};
  float m_run = -1e30f, l_run = 0.f;
  unsigned short* Pw = Plds[wave];

  for (int kv = 0; kv < S_; kv += 32) {
    // QK^T (swapped): st[s2] holds keys kv+s2*16+lg*4+r for q-row ln15
    f32x4 st[2];
#pragma unroll
    for (int s2 = 0; s2 < 2; ++s2) {
      st[s2] = (f32x4){0.f, 0.f, 0.f, 0.f};
#pragma unroll
      for (int ks = 0; ks < 2; ++ks) {
        bf16x8 kf = *(const bf16x8*)&Kb[(size_t)(kv + s2 * 16 + ln15) * 3072 + ks * 32 + lg * 8];
        st[s2] = __builtin_amdgcn_mfma_f32_16x16x32_bf16(kf, qf[ks], st[s2], 0, 0, 0);
      }
    }
    // online softmax
    float tmax = -1e30f;
#pragma unroll
    for (int s2 = 0; s2 < 2; ++s2)
#pragma unroll
      for (int r = 0; r < 4; ++r) {
        float v = st[s2][r] * sc;
        st[s2][r] = v;
        tmax = fmaxf(tmax, v);
      }
    tmax = fmaxf(tmax, __shfl_xor(tmax, 16));
    tmax = fmaxf(tmax, __shfl_xor(tmax, 32));
    float m_new = fmaxf(m_run, tmax);
    float resc = __expf(m_run - m_new);
    float tsum = 0.f;
    unsigned int pk[2][2];
#pragma unroll
    for (int s2 = 0; s2 < 2; ++s2) {
      float p0 = __expf(st[s2][0] - m_new);
      float p1 = __expf(st[s2][1] - m_new);
      float p2 = __expf(st[s2][2] - m_new);
      float p3 = __expf(st[s2][3] - m_new);
      tsum += (p0 + p1) + (p2 + p3);
      pk[s2][0] = (unsigned int)f2bf(p0) | ((unsigned int)f2bf(p1) << 16);
      pk[s2][1] = (unsigned int)f2bf(p2) | ((unsigned int)f2bf(p3) << 16);
    }
    tsum += __shfl_xor(tsum, 16);
    tsum += __shfl_xor(tsum, 32);
    l_run = l_run * resc + tsum;
    m_run = m_new;
#pragma unroll
    for (int dt = 0; dt < 4; ++dt)
#pragma unroll
      for (int r = 0; r < 4; ++r) acc[dt][r] *= resc;

    // P tile -> per-wave LDS as [qrow][key] (16x32 bf16)
    asm volatile("" ::: "memory");  // order vs previous iteration's pf read
    unsigned int* P32 = (unsigned int*)Pw;
#pragma unroll
    for (int s2 = 0; s2 < 2; ++s2) {
      int base = (ln15 * 32 + s2 * 16 + lg * 4) >> 1;  // uint units
      P32[base] = pk[s2][0];
      P32[base + 1] = pk[s2][1];
    }
    asm volatile("" ::: "memory");  // order writes before pf read
    // PV (swapped): out^T = mfma(VT_frag, P^T_frag)
    bf16x8 pf = *(const bf16x8*)&Pw[ln15 * 32 + lg * 8];
#pragma unroll
    for (int dt = 0; dt < 4; ++dt) {
      bf16x8 vf = *(const bf16x8*)&Vb[(size_t)(dt * 16 + ln15) * S_ + kv + lg * 8];
      acc[dt] = __builtin_amdgcn_mfma_f32_16x16x32_bf16(vf, pf, acc[dt], 0, 0, 0);
    }
  }
  float inv = 1.f / l_run;
  const size_t obase = ((size_t)b * S_ + blockIdx.x * 64 + wave * 16 + ln15) * D_ + h * DH_;
#pragma unroll
  for (int dt = 0; dt < 4; ++dt)
#pragma unroll
    for (int r = 0; r < 4; ++r)
      O[obase + dt * 16 + lg * 4 + r] = f2bf(acc[dt][r] * inv);
}

extern "C" void kernel_launch(void* const* d_in, const int* in_sizes, int n_in,
                              void* d_out, int out_size, void* d_ws, size_t ws_size,
                              hipStream_t stream) {
  const float* x     = (const float*)d_in[0];
  const float* w_qkv = (const float*)d_in[1];
  const float* b_qkv = (const float*)d_in[2];
  const float* w_out = (const float*)d_in[3];
  const float* b_out = (const float*)d_in[4];
  float* out = (float*)d_out;

  char* ws = (char*)d_ws;
  const size_t MiB = (size_t)1 << 20;
  unsigned short* xb   = (unsigned short*)(ws + 0 * MiB);   // 8 MiB  [4096][1024] bf16
  unsigned short* wqT  = (unsigned short*)(ws + 8 * MiB);   // 6 MiB  [3072][1024] bf16
  unsigned short* woT  = (unsigned short*)(ws + 14 * MiB);  // 2 MiB  [1024][1024] bf16
  unsigned short* qkvb = (unsigned short*)(ws + 16 * MiB);  // 24 MiB [4096][3072] bf16
  unsigned short* VTb  = (unsigned short*)(ws + 40 * MiB);  // 8 MiB  [B*H][64][2048] bf16
  unsigned short* Ab   = (unsigned short*)(ws + 48 * MiB);  // 8 MiB  [4096][1024] bf16

  k_cast<<<4096, 256, 0, stream>>>(x, xb, (B_ * S_ * D_) / 4);
  k_trcast<<<dim3(96, 32), dim3(32, 8), 0, stream>>>(w_qkv, wqT, 1024, 3072);
  k_trcast<<<dim3(32, 32), dim3(32, 8), 0, stream>>>(w_out, woT, 1024, 1024);
  k_gemm<unsigned short><<<dim3(32, 24), 256, 0, stream>>>(xb, wqT, b_qkv, qkvb, 4096, 3072, 1024);
  k_vt<<<dim3(64, 2, 32), dim3(32, 8), 0, stream>>>(qkvb, VTb);
  k_attn<<<dim3(32, 32), 256, 0, stream>>>(qkvb, VTb, Ab);
  k_gemm<float><<<dim3(32, 8), 256, 0, stream>>>(Ab, woT, b_out, out, 4096, 1024, 1024);
}

// Round 2
// 230.954 us; speedup vs baseline: 1.7121x; 1.7121x over previous
//
#include <hip/hip_runtime.h>
#include <cstdint>

#define B_ 2
#define S_ 2048
#define D_ 1024
#define H_ 16
#define DH_ 64

typedef short bf16x8 __attribute__((ext_vector_type(8)));
typedef float f32x4 __attribute__((ext_vector_type(4)));

__device__ inline unsigned short f2bf(float f) {
  unsigned int u = __float_as_uint(f);
  u += 0x7fffu + ((u >> 16) & 1u);
  return (unsigned short)(u >> 16);
}

__device__ inline float bf2f(unsigned short h) {
  return __uint_as_float(((unsigned int)h) << 16);
}

// XOR-swizzle within a 128B row: spreads the 16B column slots across banks.
__device__ inline int swz(int row, int bytecol) {
  return row * 128 + (bytecol ^ ((row & 7) << 4));
}

#define GLL(gp, lp)                                                            \
  __builtin_amdgcn_global_load_lds(                                            \
      (const __attribute__((address_space(1))) unsigned int*)(gp),             \
      (__attribute__((address_space(3))) unsigned int*)(lp), 16, 0, 0)

// ---------- cast fp32 -> bf16, vectorized x4 ----------
__global__ __launch_bounds__(256) void k_cast(const float* __restrict__ in,
                                              unsigned short* __restrict__ out, int n4) {
  int i = blockIdx.x * 256 + threadIdx.x;
  if (i >= n4) return;
  float4 v = reinterpret_cast<const float4*>(in)[i];
  ushort4 o;
  o.x = f2bf(v.x); o.y = f2bf(v.y); o.z = f2bf(v.z); o.w = f2bf(v.w);
  reinterpret_cast<ushort4*>(out)[i] = o;
}

// ---------- transpose + cast fp32 [R][C] -> bf16 [C][R] ----------
__global__ __launch_bounds__(256) void k_trcast(const float* __restrict__ in,
                                                unsigned short* __restrict__ out,
                                                int R, int C) {
  __shared__ float tile[32][33];
  int ct = blockIdx.x * 32, rt = blockIdx.y * 32;
  int tx = threadIdx.x, ty = threadIdx.y;
#pragma unroll
  for (int i = 0; i < 32; i += 8)
    tile[ty + i][tx] = in[(size_t)(rt + ty + i) * C + ct + tx];
  __syncthreads();
#pragma unroll
  for (int i = 0; i < 32; i += 8)
    out[(size_t)(ct + ty + i) * R + rt + tx] = f2bf(tile[tx][ty + i]);
}

// ---------- bf16 GEMM: C[M][N] = A[M][K] * BT[N][K]^T + bias ----------
// 128x128 tile, BK=64, 4 waves (2x2), each wave 64x64 via 16x16x32 MFMA.
// If VTout != nullptr, columns >= 2048 (the V third of qkv) are written
// transposed into VT[b,h,dh,s] instead of C.
template <typename OutT>
__global__ __launch_bounds__(256) void k_gemm(const unsigned short* __restrict__ A,
                                              const unsigned short* __restrict__ BT,
                                              const float* __restrict__ bias,
                                              OutT* __restrict__ C,
                                              unsigned short* __restrict__ VTout,
                                              int M, int N, int K) {
  __shared__ unsigned short As[128 * 64];
  __shared__ unsigned short Bs[128 * 64];
  const int t = threadIdx.x;
  const int lane = t & 63;
  const int wave = t >> 6;
  const int wm = wave >> 1, wn = wave & 1;
  const int ln15 = lane & 15, lg = lane >> 4;
  const int row0 = blockIdx.x * 128, col0 = blockIdx.y * 128;
  f32x4 acc[4][4];
#pragma unroll
  for (int i = 0; i < 4; ++i)
#pragma unroll
    for (int j = 0; j < 4; ++j)
      acc[i][j] = (f32x4){0.f, 0.f, 0.f, 0.f};

  for (int k0 = 0; k0 < K; k0 += 64) {
    __syncthreads();
#pragma unroll
    for (int i = 0; i < 4; ++i) {
      int chunk = i * 256 + t;          // 16-byte chunks; 8 chunks per 64-col row
      int r = chunk >> 3;
      int cb = (chunk & 7) * 16;
      const char* ga = (const char*)(A + (size_t)(row0 + r) * K + k0) + cb;
      const char* gb = (const char*)(BT + (size_t)(col0 + r) * K + k0) + cb;
      GLL(ga, (char*)As + chunk * 16);
      GLL(gb, (char*)Bs + chunk * 16);
    }
    __syncthreads();
#pragma unroll
    for (int ks = 0; ks < 2; ++ks) {
      bf16x8 af[4], bf[4];
#pragma unroll
      for (int mt = 0; mt < 4; ++mt)
        af[mt] = *(const bf16x8*)&As[(wm * 64 + mt * 16 + ln15) * 64 + ks * 32 + lg * 8];
#pragma unroll
      for (int nt = 0; nt < 4; ++nt)
        bf[nt] = *(const bf16x8*)&Bs[(wn * 64 + nt * 16 + ln15) * 64 + ks * 32 + lg * 8];
#pragma unroll
      for (int mt = 0; mt < 4; ++mt)
#pragma unroll
        for (int nt = 0; nt < 4; ++nt)
          acc[mt][nt] = __builtin_amdgcn_mfma_f32_16x16x32_bf16(af[mt], bf[nt], acc[mt][nt], 0, 0, 0);
    }
  }
  // epilogue: C/D layout col=lane&15, row=(lane>>4)*4+reg  [measured m89]
#pragma unroll
  for (int mt = 0; mt < 4; ++mt) {
#pragma unroll
    for (int nt = 0; nt < 4; ++nt) {
      int col = col0 + wn * 64 + nt * 16 + ln15;
      float bv = bias[col];
      if (VTout != nullptr && col >= 2048) {
        // write transposed into VT[b*16+h][dh][s]
        int hd = col - 2048;
        int row = row0 + wm * 64 + mt * 16 + lg * 4;
        int bb = row >> 11, ss = row & 2047;
        ushort4 o;
        o.x = f2bf(acc[mt][nt][0] + bv);
        o.y = f2bf(acc[mt][nt][1] + bv);
        o.z = f2bf(acc[mt][nt][2] + bv);
        o.w = f2bf(acc[mt][nt][3] + bv);
        *(ushort4*)&VTout[(((size_t)(bb * 16 + (hd >> 6)) * 64) + (hd & 63)) * 2048 + ss] = o;
      } else {
#pragma unroll
        for (int r = 0; r < 4; ++r) {
          int row = row0 + wm * 64 + mt * 16 + lg * 4 + r;
          float v = acc[mt][nt][r] + bv;
          if constexpr (sizeof(OutT) == 2)
            C[(size_t)row * N + col] = f2bf(v);
          else
            C[(size_t)row * N + col] = v;
        }
      }
    }
  }
}

// ---------- flash attention ----------
// 1D grid of 512 blocks (XCD-swizzled), 4 waves/block. Block covers 128 q-rows
// of one (b,h); each wave owns 32 q-rows. KVBLK=64; K,V staged in LDS
// (double-buffered, XOR-swizzled via pre-swizzled global source). Swapped
// QK^T: mfma(K,Q) so a q-row's scores sit in a 16-lane column group.
__global__ __launch_bounds__(256) void k_attn(const unsigned short* __restrict__ qkv,
                                              const unsigned short* __restrict__ VT,
                                              unsigned short* __restrict__ O) {
  __shared__ unsigned short Ks[2][64 * 64];
  __shared__ unsigned short Vs[2][64 * 64];
  __shared__ unsigned short Ps[4][32 * 64];

  const int bid = blockIdx.x;             // 0..511
  const int xcd = bid & 7, idx = bid >> 3;
  const int bh = xcd + (idx >> 4) * 8;    // 16 consecutive bids share one (b,h) on one XCD
  const int qblk = idx & 15;
  const int b = bh >> 4, h = bh & 15;
  const int t = threadIdx.x, wave = t >> 6, lane = t & 63;
  const int ln15 = lane & 15, lg = lane >> 4;
  const unsigned short* Qb = qkv + (size_t)b * S_ * 3072 + h * 64;
  const unsigned short* Kb = Qb + 1024;
  const unsigned short* Vb = VT + (size_t)bh * 64 * 2048;  // [dh][s]
  const int q0 = qblk * 128 + wave * 32;

  // Q fragments, pre-scaled by 1/sqrt(dh)
  bf16x8 qf[2][2];
#pragma unroll
  for (int qg = 0; qg < 2; ++qg)
#pragma unroll
    for (int ks = 0; ks < 2; ++ks) {
      bf16x8 raw = *(const bf16x8*)&Qb[(size_t)(q0 + qg * 16 + ln15) * 3072 + ks * 32 + lg * 8];
#pragma unroll
      for (int j = 0; j < 8; ++j)
        qf[qg][ks][j] = (short)f2bf(bf2f((unsigned short)raw[j]) * 0.125f);
    }

  // stage K,V tile [64 rows][64 cols] into LDS buffer bi, source pre-swizzled
  auto stage = [&](int bi, int kv) {
#pragma unroll
    for (int i = 0; i < 2; ++i) {
      int c = i * 256 + t;                 // 0..511 16B chunks
      int row = c >> 3, col = c & 7;
      int gcol = col ^ (row & 7);          // inverse swizzle on source
      GLL((const char*)(Kb + (size_t)(kv + row) * 3072 + gcol * 8),
          (char*)&Ks[bi][0] + c * 16);
      GLL((const char*)(Vb + (size_t)row * 2048 + kv + gcol * 8),
          (char*)&Vs[bi][0] + c * 16);
    }
  };

  f32x4 acc[2][4];
#pragma unroll
  for (int qg = 0; qg < 2; ++qg)
#pragma unroll
    for (int dt = 0; dt < 4; ++dt)
      acc[qg][dt] = (f32x4){0.f, 0.f, 0.f, 0.f};
  float m0 = -1e30f, m1 = -1e30f, l0 = 0.f, l1 = 0.f;
  unsigned short* Pw = Ps[wave];

  stage(0, 0);
  __syncthreads();
  int buf = 0;

  for (int kv = 0; kv < S_; kv += 64) {
    if (kv + 64 < S_) stage(buf ^ 1, kv + 64);

    // ---- QK^T (swapped): st[qg][kg], q = qg*16+ln15, key = kg*16+lg*4+r
    f32x4 st[2][4];
#pragma unroll
    for (int qg = 0; qg < 2; ++qg)
#pragma unroll
      for (int kg = 0; kg < 4; ++kg)
        st[qg][kg] = (f32x4){0.f, 0.f, 0.f, 0.f};
#pragma unroll
    for (int kg = 0; kg < 4; ++kg) {
      int krow = kg * 16 + ln15;
      bf16x8 kf0 = *(const bf16x8*)((const char*)&Ks[buf][0] + swz(krow, lg * 16));
      bf16x8 kf1 = *(const bf16x8*)((const char*)&Ks[buf][0] + swz(krow, 64 + lg * 16));
      st[0][kg] = __builtin_amdgcn_mfma_f32_16x16x32_bf16(kf0, qf[0][0], st[0][kg], 0, 0, 0);
      st[0][kg] = __builtin_amdgcn_mfma_f32_16x16x32_bf16(kf1, qf[0][1], st[0][kg], 0, 0, 0);
      st[1][kg] = __builtin_amdgcn_mfma_f32_16x16x32_bf16(kf0, qf[1][0], st[1][kg], 0, 0, 0);
      st[1][kg] = __builtin_amdgcn_mfma_f32_16x16x32_bf16(kf1, qf[1][1], st[1][kg], 0, 0, 0);
    }

    // ---- row max (16 own values, then reduce over lg via shfl 16/32)
    float tmax[2];
#pragma unroll
    for (int qg = 0; qg < 2; ++qg) {
      float tm = -1e30f;
#pragma unroll
      for (int kg = 0; kg < 4; ++kg) {
        tm = fmaxf(tm, fmaxf(fmaxf(st[qg][kg][0], st[qg][kg][1]),
                             fmaxf(st[qg][kg][2], st[qg][kg][3])));
      }
      tm = fmaxf(tm, __shfl_xor(tm, 16));
      tm = fmaxf(tm, __shfl_xor(tm, 32));
      tmax[qg] = tm;
    }

    // ---- defer-max: only rescale when some row's max grew by >8
    bool grow = (tmax[0] > m0 + 8.f) || (tmax[1] > m1 + 8.f);
    if (__any(grow)) {
      float n0 = fmaxf(m0, tmax[0]), n1 = fmaxf(m1, tmax[1]);
      float r0 = __expf(m0 - n0), r1 = __expf(m1 - n1);
      m0 = n0; m1 = n1; l0 *= r0; l1 *= r1;
#pragma unroll
      for (int dt = 0; dt < 4; ++dt) {
#pragma unroll
        for (int r = 0; r < 4; ++r) {
          acc[0][dt][r] *= r0;
          acc[1][dt][r] *= r1;
        }
      }
    }

    // ---- P = exp(st - m), pack to bf16, store to per-wave swizzled LDS tile
    asm volatile("" ::: "memory");
    float ts[2] = {0.f, 0.f};
#pragma unroll
    for (int qg = 0; qg < 2; ++qg) {
      int prow = qg * 16 + ln15;
      float mq = qg ? m1 : m0;
#pragma unroll
      for (int kg = 0; kg < 4; ++kg) {
        float p0 = __expf(st[qg][kg][0] - mq);
        float p1 = __expf(st[qg][kg][1] - mq);
        float p2 = __expf(st[qg][kg][2] - mq);
        float p3 = __expf(st[qg][kg][3] - mq);
        ts[qg] += (p0 + p1) + (p2 + p3);
        unsigned int w0, w1;
        asm("v_cvt_pk_bf16_f32 %0, %1, %2" : "=v"(w0) : "v"(p0), "v"(p1));
        asm("v_cvt_pk_bf16_f32 %0, %1, %2" : "=v"(w1) : "v"(p2), "v"(p3));
        *(uint2*)((char*)Pw + swz(prow, kg * 32 + lg * 8)) = make_uint2(w0, w1);
      }
    }
    ts[0] += __shfl_xor(ts[0], 16); ts[0] += __shfl_xor(ts[0], 32);
    ts[1] += __shfl_xor(ts[1], 16); ts[1] += __shfl_xor(ts[1], 32);
    l0 += ts[0]; l1 += ts[1];
    asm volatile("" ::: "memory");

    // ---- PV: acc[qg][dt] += V^T-frag x P^T-frag over two 32-key chunks
#pragma unroll
    for (int kc = 0; kc < 2; ++kc) {
      bf16x8 pf0 = *(const bf16x8*)((const char*)Pw + swz(ln15, kc * 64 + lg * 16));
      bf16x8 pf1 = *(const bf16x8*)((const char*)Pw + swz(16 + ln15, kc * 64 + lg * 16));
#pragma unroll
      for (int dt = 0; dt < 4; ++dt) {
        bf16x8 vf = *(const bf16x8*)((const char*)&Vs[buf][0] + swz(dt * 16 + ln15, kc * 64 + lg * 16));
        acc[0][dt] = __builtin_amdgcn_mfma_f32_16x16x32_bf16(vf, pf0, acc[0][dt], 0, 0, 0);
        acc[1][dt] = __builtin_amdgcn_mfma_f32_16x16x32_bf16(vf, pf1, acc[1][dt], 0, 0, 0);
      }
    }
    __syncthreads();
    buf ^= 1;
  }

  // ---- epilogue: out = acc / l, layout D[dh][q] -> O[b, q, h*64+dh]
  float inv0 = 1.f / l0, inv1 = 1.f / l1;
#pragma unroll
  for (int qg = 0; qg < 2; ++qg) {
    float inv = qg ? inv1 : inv0;
    size_t qglob = q0 + qg * 16 + ln15;
    size_t base = ((size_t)b * S_ + qglob) * D_ + h * 64 + lg * 4;
#pragma unroll
    for (int dt = 0; dt < 4; ++dt) {
      ushort4 o;
      o.x = f2bf(acc[qg][dt][0] * inv);
      o.y = f2bf(acc[qg][dt][1] * inv);
      o.z = f2bf(acc[qg][dt][2] * inv);
      o.w = f2bf(acc[qg][dt][3] * inv);
      *(ushort4*)&O[base + (size_t)dt * 16] = o;
    }
  }
}

extern "C" void kernel_launch(void* const* d_in, const int* in_sizes, int n_in,
                              void* d_out, int out_size, void* d_ws, size_t ws_size,
                              hipStream_t stream) {
  const float* x     = (const float*)d_in[0];
  const float* w_qkv = (const float*)d_in[1];
  const float* b_qkv = (const float*)d_in[2];
  const float* w_out = (const float*)d_in[3];
  const float* b_out = (const float*)d_in[4];
  float* out = (float*)d_out;

  char* ws = (char*)d_ws;
  const size_t MiB = (size_t)1 << 20;
  unsigned short* xb   = (unsigned short*)(ws + 0 * MiB);   // 8 MiB  [4096][1024] bf16
  unsigned short* wqT  = (unsigned short*)(ws + 8 * MiB);   // 6 MiB  [3072][1024] bf16
  unsigned short* woT  = (unsigned short*)(ws + 14 * MiB);  // 2 MiB  [1024][1024] bf16
  unsigned short* qkvb = (unsigned short*)(ws + 16 * MiB);  // 24 MiB [4096][3072] bf16 (V third unused)
  unsigned short* VTb  = (unsigned short*)(ws + 40 * MiB);  // 8 MiB  [B*H][64][2048] bf16
  unsigned short* Ab   = (unsigned short*)(ws + 48 * MiB);  // 8 MiB  [4096][1024] bf16

  k_cast<<<4096, 256, 0, stream>>>(x, xb, (B_ * S_ * D_) / 4);
  k_trcast<<<dim3(96, 32), dim3(32, 8), 0, stream>>>(w_qkv, wqT, 1024, 3072);
  k_trcast<<<dim3(32, 32), dim3(32, 8), 0, stream>>>(w_out, woT, 1024, 1024);
  k_gemm<unsigned short><<<dim3(32, 24), 256, 0, stream>>>(xb, wqT, b_qkv, qkvb, VTb, 4096, 3072, 1024);
  k_attn<<<512, 256, 0, stream>>>(qkvb, VTb, Ab);
  k_gemm<float><<<dim3(32, 8), 256, 0, stream>>>(Ab, woT, b_out, out, nullptr, 4096, 1024, 1024);
}

// Round 5
// 217.553 us; speedup vs baseline: 1.8175x; 1.0616x over previous
//
#include <hip/hip_runtime.h>
#include <cstdint>

#define B_ 2
#define S_ 2048
#define D_ 1024
#define H_ 16
#define DH_ 64

typedef short bf16x8 __attribute__((ext_vector_type(8)));
typedef float f32x4 __attribute__((ext_vector_type(4)));

__device__ inline unsigned short f2bf(float f) {
  unsigned int u = __float_as_uint(f);
  u += 0x7fffu + ((u >> 16) & 1u);
  return (unsigned short)(u >> 16);
}

__device__ inline float bf2f(unsigned short h) {
  return __uint_as_float(((unsigned int)h) << 16);
}

// fast 2^x via v_exp_f32
__device__ inline float fexp2(float x) { return __builtin_amdgcn_exp2f(x); }

// XOR-swizzle within a 128B row: spreads the 16B column slots across banks.
__device__ inline int swz(int row, int bytecol) {
  return row * 128 + (bytecol ^ ((row & 7) << 4));
}

#define GLL(gp, lp)                                                            \
  __builtin_amdgcn_global_load_lds(                                            \
      (const __attribute__((address_space(1))) unsigned int*)(gp),             \
      (__attribute__((address_space(3))) unsigned int*)(lp), 16, 0, 0)

// ---------- cast fp32 -> bf16, vectorized x4 ----------
__global__ __launch_bounds__(256) void k_cast(const float* __restrict__ in,
                                              unsigned short* __restrict__ out, int n4) {
  int i = blockIdx.x * 256 + threadIdx.x;
  if (i >= n4) return;
  float4 v = reinterpret_cast<const float4*>(in)[i];
  ushort4 o;
  o.x = f2bf(v.x); o.y = f2bf(v.y); o.z = f2bf(v.z); o.w = f2bf(v.w);
  reinterpret_cast<ushort4*>(out)[i] = o;
}

// ---------- transpose + cast fp32 [R][C] -> bf16 [C][R] ----------
__global__ __launch_bounds__(256) void k_trcast(const float* __restrict__ in,
                                                unsigned short* __restrict__ out,
                                                int R, int C) {
  __shared__ float tile[32][33];
  int ct = blockIdx.x * 32, rt = blockIdx.y * 32;
  int tx = threadIdx.x, ty = threadIdx.y;
#pragma unroll
  for (int i = 0; i < 32; i += 8)
    tile[ty + i][tx] = in[(size_t)(rt + ty + i) * C + ct + tx];
  __syncthreads();
#pragma unroll
  for (int i = 0; i < 32; i += 8)
    out[(size_t)(ct + ty + i) * R + rt + tx] = f2bf(tile[tx][ty + i]);
}

// ---------- bf16 GEMM: C[M][N] = A[M][K] * BT[N][K]^T + bias ----------
// 128x128 tile, BK=64, 4 waves (2x2), each wave 64x64 via 16x16x32 MFMA.
// If VTout != nullptr, columns >= 2048 (the V third of qkv) are written
// transposed into VT[b,h,dh,s] instead of C.
template <typename OutT>
__global__ __launch_bounds__(256) void k_gemm(const unsigned short* __restrict__ A,
                                              const unsigned short* __restrict__ BT,
                                              const float* __restrict__ bias,
                                              OutT* __restrict__ C,
                                              unsigned short* __restrict__ VTout,
                                              int M, int N, int K) {
  __shared__ unsigned short As[128 * 64];
  __shared__ unsigned short Bs[128 * 64];
  const int t = threadIdx.x;
  const int lane = t & 63;
  const int wave = t >> 6;
  const int wm = wave >> 1, wn = wave & 1;
  const int ln15 = lane & 15, lg = lane >> 4;
  const int row0 = blockIdx.x * 128, col0 = blockIdx.y * 128;
  f32x4 acc[4][4];
#pragma unroll
  for (int i = 0; i < 4; ++i)
#pragma unroll
    for (int j = 0; j < 4; ++j)
      acc[i][j] = (f32x4){0.f, 0.f, 0.f, 0.f};

  for (int k0 = 0; k0 < K; k0 += 64) {
    __syncthreads();
#pragma unroll
    for (int i = 0; i < 4; ++i) {
      int chunk = i * 256 + t;          // 16-byte chunks; 8 chunks per 64-col row
      int r = chunk >> 3;
      int cb = (chunk & 7) * 16;
      const char* ga = (const char*)(A + (size_t)(row0 + r) * K + k0) + cb;
      const char* gb = (const char*)(BT + (size_t)(col0 + r) * K + k0) + cb;
      GLL(ga, (char*)As + chunk * 16);
      GLL(gb, (char*)Bs + chunk * 16);
    }
    __syncthreads();
#pragma unroll
    for (int ks = 0; ks < 2; ++ks) {
      bf16x8 af[4], bf[4];
#pragma unroll
      for (int mt = 0; mt < 4; ++mt)
        af[mt] = *(const bf16x8*)&As[(wm * 64 + mt * 16 + ln15) * 64 + ks * 32 + lg * 8];
#pragma unroll
      for (int nt = 0; nt < 4; ++nt)
        bf[nt] = *(const bf16x8*)&Bs[(wn * 64 + nt * 16 + ln15) * 64 + ks * 32 + lg * 8];
#pragma unroll
      for (int mt = 0; mt < 4; ++mt)
#pragma unroll
        for (int nt = 0; nt < 4; ++nt)
          acc[mt][nt] = __builtin_amdgcn_mfma_f32_16x16x32_bf16(af[mt], bf[nt], acc[mt][nt], 0, 0, 0);
    }
  }
  // epilogue: C/D layout col=lane&15, row=(lane>>4)*4+reg  [measured m89]
#pragma unroll
  for (int mt = 0; mt < 4; ++mt) {
#pragma unroll
    for (int nt = 0; nt < 4; ++nt) {
      int col = col0 + wn * 64 + nt * 16 + ln15;
      float bv = bias[col];
      if (VTout != nullptr && col >= 2048) {
        // write transposed into VT[b*16+h][dh][s]
        int hd = col - 2048;
        int row = row0 + wm * 64 + mt * 16 + lg * 4;
        int bb = row >> 11, ss = row & 2047;
        ushort4 o;
        o.x = f2bf(acc[mt][nt][0] + bv);
        o.y = f2bf(acc[mt][nt][1] + bv);
        o.z = f2bf(acc[mt][nt][2] + bv);
        o.w = f2bf(acc[mt][nt][3] + bv);
        *(ushort4*)&VTout[(((size_t)(bb * 16 + (hd >> 6)) * 64) + (hd & 63)) * 2048 + ss] = o;
      } else {
#pragma unroll
        for (int r = 0; r < 4; ++r) {
          int row = row0 + wm * 64 + mt * 16 + lg * 4 + r;
          float v = acc[mt][nt][r] + bv;
          if constexpr (sizeof(OutT) == 2)
            C[(size_t)row * N + col] = f2bf(v);
          else
            C[(size_t)row * N + col] = v;
        }
      }
    }
  }
}

// ---------- flash attention ----------
// 512 blocks (XCD-swizzled) x 512 threads (8 waves). Block covers 128 q-rows
// of one (b,h); each wave owns 16 q-rows. KVBLK=64; K,V staged in LDS
// (double-buffered, XOR-swizzled via pre-swizzled global source). Swapped
// QK^T: mfma(K,Q) so a q-row's scores sit in a 16-lane column group.
// Softmax in exp2 domain: Q pre-scaled by (1/sqrt(dh))*log2(e).
__global__ __launch_bounds__(512) void k_attn(const unsigned short* __restrict__ qkv,
                                              const unsigned short* __restrict__ VT,
                                              unsigned short* __restrict__ O) {
  __shared__ unsigned short Ks[2][64 * 64];
  __shared__ unsigned short Vs[2][64 * 64];
  __shared__ unsigned short Ps[8][16 * 64];

  const int bid = blockIdx.x;             // 0..511
  const int xcd = bid & 7, idx = bid >> 3;
  const int bh = xcd + (idx >> 4) * 8;    // 16 consecutive bids share one (b,h) on one XCD
  const int qblk = idx & 15;
  const int b = bh >> 4, h = bh & 15;
  const int t = threadIdx.x, wave = t >> 6, lane = t & 63;
  const int ln15 = lane & 15, lg = lane >> 4;
  const unsigned short* Qb = qkv + (size_t)b * S_ * 3072 + h * 64;
  const unsigned short* Kb = Qb + 1024;
  const unsigned short* Vb = VT + (size_t)bh * 64 * 2048;  // [dh][s]
  const int q0 = qblk * 128 + wave * 16;

  // Q fragments, pre-scaled by (1/sqrt(dh)) * log2(e) for exp2-domain softmax
  const float qsc = 0.125f * 1.4426950408889634f;
  bf16x8 qf[2];
#pragma unroll
  for (int ks = 0; ks < 2; ++ks) {
    bf16x8 raw = *(const bf16x8*)&Qb[(size_t)(q0 + ln15) * 3072 + ks * 32 + lg * 8];
#pragma unroll
    for (int j = 0; j < 8; ++j)
      qf[ks][j] = (short)f2bf(bf2f((unsigned short)raw[j]) * qsc);
  }

  // stage K,V tile [64 rows][64 cols] into LDS buffer bi, source pre-swizzled
  auto stage = [&](int bi, int kv) {
    int row = t >> 3, col = t & 7;         // 512 threads = 512 16B chunks
    int gcol = col ^ (row & 7);            // inverse swizzle on source
    GLL((const char*)(Kb + (size_t)(kv + row) * 3072 + gcol * 8),
        (char*)&Ks[bi][0] + t * 16);
    GLL((const char*)(Vb + (size_t)row * 2048 + kv + gcol * 8),
        (char*)&Vs[bi][0] + t * 16);
  };

  f32x4 acc[4];
#pragma unroll
  for (int dt = 0; dt < 4; ++dt)
    acc[dt] = (f32x4){0.f, 0.f, 0.f, 0.f};
  float m0 = -1e30f, l0 = 0.f;
  unsigned short* Pw = Ps[wave];

  stage(0, 0);
  __syncthreads();
  int buf = 0;

  for (int kv = 0; kv < S_; kv += 64) {
    if (kv + 64 < S_) stage(buf ^ 1, kv + 64);

    // ---- QK^T (swapped): st[kg], q = ln15, key = kg*16+lg*4+r
    f32x4 st[4];
#pragma unroll
    for (int kg = 0; kg < 4; ++kg)
      st[kg] = (f32x4){0.f, 0.f, 0.f, 0.f};
#pragma unroll
    for (int kg = 0; kg < 4; ++kg) {
      int krow = kg * 16 + ln15;
      bf16x8 kf0 = *(const bf16x8*)((const char*)&Ks[buf][0] + swz(krow, lg * 16));
      bf16x8 kf1 = *(const bf16x8*)((const char*)&Ks[buf][0] + swz(krow, 64 + lg * 16));
      st[kg] = __builtin_amdgcn_mfma_f32_16x16x32_bf16(kf0, qf[0], st[kg], 0, 0, 0);
      st[kg] = __builtin_amdgcn_mfma_f32_16x16x32_bf16(kf1, qf[1], st[kg], 0, 0, 0);
    }

    // ---- row max (16 own values, then reduce over lg via shfl 16/32)
    float tm = -1e30f;
#pragma unroll
    for (int kg = 0; kg < 4; ++kg)
      tm = fmaxf(tm, fmaxf(fmaxf(st[kg][0], st[kg][1]),
                           fmaxf(st[kg][2], st[kg][3])));
    tm = fmaxf(tm, __shfl_xor(tm, 16));
    tm = fmaxf(tm, __shfl_xor(tm, 32));

    // ---- defer-max (log2 domain): rescale only when max grew by >11
    if (__any(tm > m0 + 11.0f)) {
      float n0 = fmaxf(m0, tm);
      float r0 = fexp2(m0 - n0);
      m0 = n0; l0 *= r0;
#pragma unroll
      for (int dt = 0; dt < 4; ++dt)
#pragma unroll
        for (int r = 0; r < 4; ++r)
          acc[dt][r] *= r0;
    }

    // ---- P = exp2(st - m), pack to bf16, store to per-wave swizzled LDS tile
    asm volatile("" ::: "memory");
    float ts = 0.f;
#pragma unroll
    for (int kg = 0; kg < 4; ++kg) {
      float p0 = fexp2(st[kg][0] - m0);
      float p1 = fexp2(st[kg][1] - m0);
      float p2 = fexp2(st[kg][2] - m0);
      float p3 = fexp2(st[kg][3] - m0);
      ts += (p0 + p1) + (p2 + p3);
      unsigned int w0, w1;
      asm("v_cvt_pk_bf16_f32 %0, %1, %2" : "=v"(w0) : "v"(p0), "v"(p1));
      asm("v_cvt_pk_bf16_f32 %0, %1, %2" : "=v"(w1) : "v"(p2), "v"(p3));
      *(uint2*)((char*)Pw + swz(ln15, kg * 32 + lg * 8)) = make_uint2(w0, w1);
    }
    ts += __shfl_xor(ts, 16);
    ts += __shfl_xor(ts, 32);
    l0 += ts;
    asm volatile("" ::: "memory");

    // ---- PV: acc[dt] += V^T-frag x P^T-frag over two 32-key chunks
#pragma unroll
    for (int kc = 0; kc < 2; ++kc) {
      bf16x8 pf = *(const bf16x8*)((const char*)Pw + swz(ln15, kc * 64 + lg * 16));
#pragma unroll
      for (int dt = 0; dt < 4; ++dt) {
        bf16x8 vf = *(const bf16x8*)((const char*)&Vs[buf][0] + swz(dt * 16 + ln15, kc * 64 + lg * 16));
        acc[dt] = __builtin_amdgcn_mfma_f32_16x16x32_bf16(vf, pf, acc[dt], 0, 0, 0);
      }
    }
    __syncthreads();
    buf ^= 1;
  }

  // ---- epilogue: out = acc / l, layout D[dh][q] -> O[b, q, h*64+dh]
  float inv = 1.f / l0;
  size_t qglob = q0 + ln15;
  size_t base = ((size_t)b * S_ + qglob) * D_ + h * 64 + lg * 4;
#pragma unroll
  for (int dt = 0; dt < 4; ++dt) {
    ushort4 o;
    o.x = f2bf(acc[dt][0] * inv);
    o.y = f2bf(acc[dt][1] * inv);
    o.z = f2bf(acc[dt][2] * inv);
    o.w = f2bf(acc[dt][3] * inv);
    *(ushort4*)&O[base + (size_t)dt * 16] = o;
  }
}

extern "C" void kernel_launch(void* const* d_in, const int* in_sizes, int n_in,
                              void* d_out, int out_size, void* d_ws, size_t ws_size,
                              hipStream_t stream) {
  const float* x     = (const float*)d_in[0];
  const float* w_qkv = (const float*)d_in[1];
  const float* b_qkv = (const float*)d_in[2];
  const float* w_out = (const float*)d_in[3];
  const float* b_out = (const float*)d_in[4];
  float* out = (float*)d_out;

  char* ws = (char*)d_ws;
  const size_t MiB = (size_t)1 << 20;
  unsigned short* xb   = (unsigned short*)(ws + 0 * MiB);   // 8 MiB  [4096][1024] bf16
  unsigned short* wqT  = (unsigned short*)(ws + 8 * MiB);   // 6 MiB  [3072][1024] bf16
  unsigned short* woT  = (unsigned short*)(ws + 14 * MiB);  // 2 MiB  [1024][1024] bf16
  unsigned short* qkvb = (unsigned short*)(ws + 16 * MiB);  // 24 MiB [4096][3072] bf16 (V third unused)
  unsigned short* VTb  = (unsigned short*)(ws + 40 * MiB);  // 8 MiB  [B*H][64][2048] bf16
  unsigned short* Ab   = (unsigned short*)(ws + 48 * MiB);  // 8 MiB  [4096][1024] bf16

  k_cast<<<4096, 256, 0, stream>>>(x, xb, (B_ * S_ * D_) / 4);
  k_trcast<<<dim3(96, 32), dim3(32, 8), 0, stream>>>(w_qkv, wqT, 1024, 3072);
  k_trcast<<<dim3(32, 32), dim3(32, 8), 0, stream>>>(w_out, woT, 1024, 1024);
  k_gemm<unsigned short><<<dim3(32, 24), 256, 0, stream>>>(xb, wqT, b_qkv, qkvb, VTb, 4096, 3072, 1024);
  k_attn<<<512, 512, 0, stream>>>(qkvb, VTb, Ab);
  k_gemm<float><<<dim3(32, 8), 256, 0, stream>>>(Ab, woT, b_out, out, nullptr, 4096, 1024, 1024);
}

// Round 6
// 215.571 us; speedup vs baseline: 1.8343x; 1.0092x over previous
//
#include <hip/hip_runtime.h>
#include <cstdint>

#define B_ 2
#define S_ 2048
#define D_ 1024
#define H_ 16
#define DH_ 64

typedef short bf16x8 __attribute__((ext_vector_type(8)));
typedef float f32x4 __attribute__((ext_vector_type(4)));

__device__ inline unsigned short f2bf(float f) {
  unsigned int u = __float_as_uint(f);
  u += 0x7fffu + ((u >> 16) & 1u);
  return (unsigned short)(u >> 16);
}

__device__ inline float bf2f(unsigned short h) {
  return __uint_as_float(((unsigned int)h) << 16);
}

// fast 2^x via v_exp_f32
__device__ inline float fexp2(float x) { return __builtin_amdgcn_exp2f(x); }

// XOR-swizzle within a 128B row: spreads the 16B column slots across banks.
__device__ inline int swz(int row, int bytecol) {
  return row * 128 + (bytecol ^ ((row & 7) << 4));
}

#define GLL(gp, lp)                                                            \
  __builtin_amdgcn_global_load_lds(                                            \
      (const __attribute__((address_space(1))) unsigned int*)(gp),             \
      (__attribute__((address_space(3))) unsigned int*)(lp), 16, 0, 0)

// ---------- cast fp32 -> bf16, vectorized x4 ----------
__global__ __launch_bounds__(256) void k_cast(const float* __restrict__ in,
                                              unsigned short* __restrict__ out, int n4) {
  int i = blockIdx.x * 256 + threadIdx.x;
  if (i >= n4) return;
  float4 v = reinterpret_cast<const float4*>(in)[i];
  ushort4 o;
  o.x = f2bf(v.x); o.y = f2bf(v.y); o.z = f2bf(v.z); o.w = f2bf(v.w);
  reinterpret_cast<ushort4*>(out)[i] = o;
}

// ---------- transpose + cast fp32 [R][C] -> bf16 [C][R] ----------
__global__ __launch_bounds__(256) void k_trcast(const float* __restrict__ in,
                                                unsigned short* __restrict__ out,
                                                int R, int C) {
  __shared__ float tile[32][33];
  int ct = blockIdx.x * 32, rt = blockIdx.y * 32;
  int tx = threadIdx.x, ty = threadIdx.y;
#pragma unroll
  for (int i = 0; i < 32; i += 8)
    tile[ty + i][tx] = in[(size_t)(rt + ty + i) * C + ct + tx];
  __syncthreads();
#pragma unroll
  for (int i = 0; i < 32; i += 8)
    out[(size_t)(ct + ty + i) * R + rt + tx] = f2bf(tile[tx][ty + i]);
}

// ---------- bf16 GEMM: C[M][N] = A[M][K] * BT[N][K]^T + bias ----------
// Tile BM x BN, BK=64, 4 waves (2x2), wave tile (BM/2)x(BN/2), 16x16x32 MFMA.
// XCD-aware bijective block swizzle (requires nwg % 8 == 0).
// If VTout != nullptr, columns >= 2048 (the V third of qkv) are written
// transposed into VT[b,h,dh,s] instead of C.
template <int BM, int BN, typename OutT>
__global__ __launch_bounds__(256) void k_gemm(const unsigned short* __restrict__ A,
                                              const unsigned short* __restrict__ BT,
                                              const float* __restrict__ bias,
                                              OutT* __restrict__ C,
                                              unsigned short* __restrict__ VTout,
                                              int M, int N, int K) {
  constexpr int MT = BM / 32, NT = BN / 32;
  __shared__ unsigned short As[BM * 64];
  __shared__ unsigned short Bs[BN * 64];
  const int t = threadIdx.x;
  const int lane = t & 63;
  const int wave = t >> 6;
  const int wm = wave >> 1, wn = wave & 1;
  const int ln15 = lane & 15, lg = lane >> 4;
  // XCD-aware swizzle: 8 XCDs, contiguous chunk per XCD
  const int nwg = gridDim.x * gridDim.y;
  const int flat = blockIdx.y * gridDim.x + blockIdx.x;
  const int cpx = nwg >> 3;
  const int sid = (flat & 7) * cpx + (flat >> 3);
  const int row0 = (sid % gridDim.x) * BM, col0 = (sid / gridDim.x) * BN;
  f32x4 acc[MT][NT];
#pragma unroll
  for (int i = 0; i < MT; ++i)
#pragma unroll
    for (int j = 0; j < NT; ++j)
      acc[i][j] = (f32x4){0.f, 0.f, 0.f, 0.f};

  for (int k0 = 0; k0 < K; k0 += 64) {
    __syncthreads();
#pragma unroll
    for (int i = 0; i < BM / 32; ++i) {
      int chunk = i * 256 + t;          // 16-byte chunks; 8 chunks per 64-col row
      int r = chunk >> 3;
      int cb = (chunk & 7) * 16;
      GLL((const char*)(A + (size_t)(row0 + r) * K + k0) + cb, (char*)As + chunk * 16);
    }
#pragma unroll
    for (int i = 0; i < BN / 32; ++i) {
      int chunk = i * 256 + t;
      int r = chunk >> 3;
      int cb = (chunk & 7) * 16;
      GLL((const char*)(BT + (size_t)(col0 + r) * K + k0) + cb, (char*)Bs + chunk * 16);
    }
    __syncthreads();
#pragma unroll
    for (int ks = 0; ks < 2; ++ks) {
      bf16x8 af[MT], bf[NT];
#pragma unroll
      for (int mt = 0; mt < MT; ++mt)
        af[mt] = *(const bf16x8*)&As[(wm * (BM / 2) + mt * 16 + ln15) * 64 + ks * 32 + lg * 8];
#pragma unroll
      for (int nt = 0; nt < NT; ++nt)
        bf[nt] = *(const bf16x8*)&Bs[(wn * (BN / 2) + nt * 16 + ln15) * 64 + ks * 32 + lg * 8];
#pragma unroll
      for (int mt = 0; mt < MT; ++mt)
#pragma unroll
        for (int nt = 0; nt < NT; ++nt)
          acc[mt][nt] = __builtin_amdgcn_mfma_f32_16x16x32_bf16(af[mt], bf[nt], acc[mt][nt], 0, 0, 0);
    }
  }
  // epilogue: C/D layout col=lane&15, row=(lane>>4)*4+reg  [measured m89]
#pragma unroll
  for (int mt = 0; mt < MT; ++mt) {
#pragma unroll
    for (int nt = 0; nt < NT; ++nt) {
      int col = col0 + wn * (BN / 2) + nt * 16 + ln15;
      float bv = bias[col];
      if (VTout != nullptr && col >= 2048) {
        // write transposed into VT[b*16+h][dh][s]
        int hd = col - 2048;
        int row = row0 + wm * (BM / 2) + mt * 16 + lg * 4;
        int bb = row >> 11, ss = row & 2047;
        ushort4 o;
        o.x = f2bf(acc[mt][nt][0] + bv);
        o.y = f2bf(acc[mt][nt][1] + bv);
        o.z = f2bf(acc[mt][nt][2] + bv);
        o.w = f2bf(acc[mt][nt][3] + bv);
        *(ushort4*)&VTout[(((size_t)(bb * 16 + (hd >> 6)) * 64) + (hd & 63)) * 2048 + ss] = o;
      } else {
#pragma unroll
        for (int r = 0; r < 4; ++r) {
          int row = row0 + wm * (BM / 2) + mt * 16 + lg * 4 + r;
          float v = acc[mt][nt][r] + bv;
          if constexpr (sizeof(OutT) == 2)
            C[(size_t)row * N + col] = f2bf(v);
          else
            C[(size_t)row * N + col] = v;
        }
      }
    }
  }
}

// ---------- flash attention ----------
// 512 blocks (XCD-swizzled) x 512 threads (8 waves). Block covers 128 q-rows
// of one (b,h); each wave owns 16 q-rows. KVBLK=64; K,V staged in LDS
// (double-buffered, XOR-swizzled via pre-swizzled global source). Swapped
// QK^T: mfma(K,Q) so a q-row's scores sit in a 16-lane column group.
// Softmax in exp2 domain: Q pre-scaled by (1/sqrt(dh))*log2(e).
__global__ __launch_bounds__(512) void k_attn(const unsigned short* __restrict__ qkv,
                                              const unsigned short* __restrict__ VT,
                                              unsigned short* __restrict__ O) {
  __shared__ unsigned short Ks[2][64 * 64];
  __shared__ unsigned short Vs[2][64 * 64];
  __shared__ unsigned short Ps[8][16 * 64];

  const int bid = blockIdx.x;             // 0..511
  const int xcd = bid & 7, idx = bid >> 3;
  const int bh = xcd + (idx >> 4) * 8;    // 16 consecutive bids share one (b,h) on one XCD
  const int qblk = idx & 15;
  const int b = bh >> 4, h = bh & 15;
  const int t = threadIdx.x, wave = t >> 6, lane = t & 63;
  const int ln15 = lane & 15, lg = lane >> 4;
  const unsigned short* Qb = qkv + (size_t)b * S_ * 3072 + h * 64;
  const unsigned short* Kb = Qb + 1024;
  const unsigned short* Vb = VT + (size_t)bh * 64 * 2048;  // [dh][s]
  const int q0 = qblk * 128 + wave * 16;

  // Q fragments, pre-scaled by (1/sqrt(dh)) * log2(e) for exp2-domain softmax
  const float qsc = 0.125f * 1.4426950408889634f;
  bf16x8 qf[2];
#pragma unroll
  for (int ks = 0; ks < 2; ++ks) {
    bf16x8 raw = *(const bf16x8*)&Qb[(size_t)(q0 + ln15) * 3072 + ks * 32 + lg * 8];
#pragma unroll
    for (int j = 0; j < 8; ++j)
      qf[ks][j] = (short)f2bf(bf2f((unsigned short)raw[j]) * qsc);
  }

  // hoisted staging addresses (row = t>>3, swizzled col = (t&7)^(row&7))
  const int srow = t >> 3;
  const int scol = (t & 7) ^ (srow & 7);
  const unsigned short* kPtr0 = Kb + (size_t)srow * 3072 + scol * 8;
  const unsigned short* vPtr0 = Vb + (size_t)srow * 2048 + scol * 8;
  char* ldsK0 = (char*)&Ks[0][0] + t * 16;
  char* ldsV0 = (char*)&Vs[0][0] + t * 16;

  auto stage = [&](int bi, int kv) {
    GLL(kPtr0 + (size_t)kv * 3072, ldsK0 + bi * 8192);
    GLL(vPtr0 + kv, ldsV0 + bi * 8192);
  };

  f32x4 acc[4];
#pragma unroll
  for (int dt = 0; dt < 4; ++dt)
    acc[dt] = (f32x4){0.f, 0.f, 0.f, 0.f};
  float m0 = -1e30f, l0 = 0.f;
  unsigned short* Pw = Ps[wave];

  stage(0, 0);
  __syncthreads();
  int buf = 0;

  for (int kv = 0; kv < S_; kv += 64) {
    if (kv + 64 < S_) stage(buf ^ 1, kv + 64);

    // ---- QK^T (swapped): st[kg], q = ln15, key = kg*16+lg*4+r
    f32x4 st[4];
#pragma unroll
    for (int kg = 0; kg < 4; ++kg)
      st[kg] = (f32x4){0.f, 0.f, 0.f, 0.f};
    __builtin_amdgcn_s_setprio(1);
#pragma unroll
    for (int kg = 0; kg < 4; ++kg) {
      int krow = kg * 16 + ln15;
      bf16x8 kf0 = *(const bf16x8*)((const char*)&Ks[buf][0] + swz(krow, lg * 16));
      bf16x8 kf1 = *(const bf16x8*)((const char*)&Ks[buf][0] + swz(krow, 64 + lg * 16));
      st[kg] = __builtin_amdgcn_mfma_f32_16x16x32_bf16(kf0, qf[0], st[kg], 0, 0, 0);
      st[kg] = __builtin_amdgcn_mfma_f32_16x16x32_bf16(kf1, qf[1], st[kg], 0, 0, 0);
    }
    __builtin_amdgcn_s_setprio(0);

    // ---- row max (16 own values, then reduce over lg via shfl 16/32)
    float tm = -1e30f;
#pragma unroll
    for (int kg = 0; kg < 4; ++kg)
      tm = fmaxf(tm, fmaxf(fmaxf(st[kg][0], st[kg][1]),
                           fmaxf(st[kg][2], st[kg][3])));
    tm = fmaxf(tm, __shfl_xor(tm, 16));
    tm = fmaxf(tm, __shfl_xor(tm, 32));

    // ---- defer-max (log2 domain): rescale only when max grew by >11
    if (__any(tm > m0 + 11.0f)) {
      float n0 = fmaxf(m0, tm);
      float r0 = fexp2(m0 - n0);
      m0 = n0; l0 *= r0;
#pragma unroll
      for (int dt = 0; dt < 4; ++dt)
#pragma unroll
        for (int r = 0; r < 4; ++r)
          acc[dt][r] *= r0;
    }

    // ---- P = exp2(st - m), pack to bf16, store to per-wave swizzled LDS tile
    asm volatile("" ::: "memory");
    float ts = 0.f;
#pragma unroll
    for (int kg = 0; kg < 4; ++kg) {
      float p0 = fexp2(st[kg][0] - m0);
      float p1 = fexp2(st[kg][1] - m0);
      float p2 = fexp2(st[kg][2] - m0);
      float p3 = fexp2(st[kg][3] - m0);
      ts += (p0 + p1) + (p2 + p3);
      unsigned int w0, w1;
      asm("v_cvt_pk_bf16_f32 %0, %1, %2" : "=v"(w0) : "v"(p0), "v"(p1));
      asm("v_cvt_pk_bf16_f32 %0, %1, %2" : "=v"(w1) : "v"(p2), "v"(p3));
      *(uint2*)((char*)Pw + swz(ln15, kg * 32 + lg * 8)) = make_uint2(w0, w1);
    }
    ts += __shfl_xor(ts, 16);
    ts += __shfl_xor(ts, 32);
    l0 += ts;
    asm volatile("" ::: "memory");

    // ---- PV: acc[dt] += V^T-frag x P^T-frag over two 32-key chunks
    __builtin_amdgcn_s_setprio(1);
#pragma unroll
    for (int kc = 0; kc < 2; ++kc) {
      bf16x8 pf = *(const bf16x8*)((const char*)Pw + swz(ln15, kc * 64 + lg * 16));
#pragma unroll
      for (int dt = 0; dt < 4; ++dt) {
        bf16x8 vf = *(const bf16x8*)((const char*)&Vs[buf][0] + swz(dt * 16 + ln15, kc * 64 + lg * 16));
        acc[dt] = __builtin_amdgcn_mfma_f32_16x16x32_bf16(vf, pf, acc[dt], 0, 0, 0);
      }
    }
    __builtin_amdgcn_s_setprio(0);
    __syncthreads();
    buf ^= 1;
  }

  // ---- epilogue: out = acc / l, layout D[dh][q] -> O[b, q, h*64+dh]
  float inv = 1.f / l0;
  size_t qglob = q0 + ln15;
  size_t base = ((size_t)b * S_ + qglob) * D_ + h * 64 + lg * 4;
#pragma unroll
  for (int dt = 0; dt < 4; ++dt) {
    ushort4 o;
    o.x = f2bf(acc[dt][0] * inv);
    o.y = f2bf(acc[dt][1] * inv);
    o.z = f2bf(acc[dt][2] * inv);
    o.w = f2bf(acc[dt][3] * inv);
    *(ushort4*)&O[base + (size_t)dt * 16] = o;
  }
}

extern "C" void kernel_launch(void* const* d_in, const int* in_sizes, int n_in,
                              void* d_out, int out_size, void* d_ws, size_t ws_size,
                              hipStream_t stream) {
  const float* x     = (const float*)d_in[0];
  const float* w_qkv = (const float*)d_in[1];
  const float* b_qkv = (const float*)d_in[2];
  const float* w_out = (const float*)d_in[3];
  const float* b_out = (const float*)d_in[4];
  float* out = (float*)d_out;

  char* ws = (char*)d_ws;
  const size_t MiB = (size_t)1 << 20;
  unsigned short* xb   = (unsigned short*)(ws + 0 * MiB);   // 8 MiB  [4096][1024] bf16
  unsigned short* wqT  = (unsigned short*)(ws + 8 * MiB);   // 6 MiB  [3072][1024] bf16
  unsigned short* woT  = (unsigned short*)(ws + 14 * MiB);  // 2 MiB  [1024][1024] bf16
  unsigned short* qkvb = (unsigned short*)(ws + 16 * MiB);  // 24 MiB [4096][3072] bf16 (V third unused)
  unsigned short* VTb  = (unsigned short*)(ws + 40 * MiB);  // 8 MiB  [B*H][64][2048] bf16
  unsigned short* Ab   = (unsigned short*)(ws + 48 * MiB);  // 8 MiB  [4096][1024] bf16

  k_cast<<<4096, 256, 0, stream>>>(x, xb, (B_ * S_ * D_) / 4);
  k_trcast<<<dim3(96, 32), dim3(32, 8), 0, stream>>>(w_qkv, wqT, 1024, 3072);
  k_trcast<<<dim3(32, 32), dim3(32, 8), 0, stream>>>(w_out, woT, 1024, 1024);
  k_gemm<128, 128, unsigned short><<<dim3(32, 24), 256, 0, stream>>>(xb, wqT, b_qkv, qkvb, VTb, 4096, 3072, 1024);
  k_attn<<<512, 512, 0, stream>>>(qkvb, VTb, Ab);
  k_gemm<64, 64, float><<<dim3(64, 16), 256, 0, stream>>>(Ab, woT, b_out, out, nullptr, 4096, 1024, 1024);
}